// Round 1
// baseline (1178.101 us; speedup 1.0000x reference)
//
#include <hip/hip_runtime.h>
#include <cstddef>
#include <cstdint>

#define HW 65536

// ---------------------------------------------------------------------------
// Kernel A: per-pixel channel LayerNorm (32ch) + 1x1 convs (32->128 q, 32->256 kv)
// One thread per pixel. Weights staged in LDS, read as wave-uniform float4
// broadcasts (4 FMA per LDS instr).
// ---------------------------------------------------------------------------
__global__ __launch_bounds__(256) void k_ln_conv1(
    const float* __restrict__ lms, const float* __restrict__ pan,
    const float* __restrict__ g_ms, const float* __restrict__ g_pan,
    const float* __restrict__ qw1, const float* __restrict__ qb1,
    const float* __restrict__ kvw1, const float* __restrict__ kvb1,
    float* __restrict__ q_pre, float* __restrict__ kv_pre)
{
    __shared__ float wq[128 * 32];
    __shared__ float wkv[256 * 32];
    const int t = threadIdx.x;
    for (int i = t; i < 128 * 32; i += 256) wq[i] = qw1[i];
    for (int i = t; i < 256 * 32; i += 256) wkv[i] = kvw1[i];
    __syncthreads();

    const int p = blockIdx.x * 256 + t;
    float x[32];

    // ---- pan -> LN -> q 1x1 ----
    {
        float s = 0.f, ss = 0.f;
        #pragma unroll
        for (int c = 0; c < 32; c++) {
            float v = pan[c * HW + p];
            x[c] = v; s += v; ss += v * v;
        }
        float mean = s * (1.f / 32.f);
        float var  = ss * (1.f / 32.f) - mean * mean;
        float rs = rsqrtf(var + 1e-5f);
        #pragma unroll
        for (int c = 0; c < 32; c++) x[c] = (x[c] - mean) * rs * g_pan[c];

        for (int o = 0; o < 128; o++) {
            const float4* w4 = (const float4*)(wq + o * 32);
            float a = qb1[o];
            #pragma unroll
            for (int i4 = 0; i4 < 8; i4++) {
                float4 w = w4[i4];
                a += x[i4*4+0]*w.x + x[i4*4+1]*w.y + x[i4*4+2]*w.z + x[i4*4+3]*w.w;
            }
            q_pre[o * HW + p] = a;
        }
    }
    // ---- lms -> LN -> kv 1x1 ----
    {
        float s = 0.f, ss = 0.f;
        #pragma unroll
        for (int c = 0; c < 32; c++) {
            float v = lms[c * HW + p];
            x[c] = v; s += v; ss += v * v;
        }
        float mean = s * (1.f / 32.f);
        float var  = ss * (1.f / 32.f) - mean * mean;
        float rs = rsqrtf(var + 1e-5f);
        #pragma unroll
        for (int c = 0; c < 32; c++) x[c] = (x[c] - mean) * rs * g_ms[c];

        for (int o = 0; o < 256; o++) {
            const float4* w4 = (const float4*)(wkv + o * 32);
            float a = kvb1[o];
            #pragma unroll
            for (int i4 = 0; i4 < 8; i4++) {
                float4 w = w4[i4];
                a += x[i4*4+0]*w.x + x[i4*4+1]*w.y + x[i4*4+2]*w.z + x[i4*4+3]*w.w;
            }
            kv_pre[o * HW + p] = a;
        }
    }
}

// ---------------------------------------------------------------------------
// Kernel B: depthwise 3x3 conv (SAME, zero pad) + bias.
// Block = (channel, strip of 8 rows). Rows staged in LDS with zero-padded ends.
// Output written directly in WINDOWED layout [c][wi][m] so the attention
// kernel reads coalesced:  wi=(hp%16)*16+(wp%16), m=(hp/16)*16+(wp/16).
// (4B/lane scattered stores; same-block lines fully covered -> L2 merges.)
// ---------------------------------------------------------------------------
__global__ __launch_bounds__(256) void k_dw3x3(
    const float* __restrict__ src, const float* __restrict__ w9,
    const float* __restrict__ bias, float* __restrict__ dst)
{
    const int t  = threadIdx.x;
    const int c  = blockIdx.x >> 5;
    const int rb = blockIdx.x & 31;
    const int r0 = rb * 8;
    __shared__ float rows[10][258];
    for (int r = 0; r < 10; r++) {
        int hp = r0 + r - 1;
        rows[r][t + 1] = (hp >= 0 && hp < 256) ? src[c * HW + hp * 256 + t] : 0.f;
    }
    if (t < 10) { rows[t][0] = 0.f; rows[t][257] = 0.f; }
    __syncthreads();

    float w[9];
    #pragma unroll
    for (int k = 0; k < 9; k++) w[k] = w9[c * 9 + k];
    const float b = bias[c];
    const int jc = t & 15;   // wp % 16 -> window col
    const int j1 = t >> 4;   // wp / 16 -> m col

    for (int r = 0; r < 8; r++) {
        const int hp = r0 + r;
        float acc = b;
        #pragma unroll
        for (int dy = 0; dy < 3; dy++) {
            const float* rr = rows[r + dy];
            acc += rr[t] * w[dy*3] + rr[t+1] * w[dy*3+1] + rr[t+2] * w[dy*3+2];
        }
        const int wi = (hp & 15) * 16 + jc;
        const int m  = (hp >> 4) * 16 + j1;
        dst[(c * 256 + wi) * 256 + m] = acc;
    }
}

// ---------------------------------------------------------------------------
// Kernel C: attention for one (window, head) per block. 256 threads.
//  - K/V tiles (16x256 each) in LDS; k-norm folded into Q registers.
//  - lane owns m = 4*lane..4*lane+3 (Q in 64 VGPRs); waves split n 4-ways.
//  - pass 1: online (max, sumexp); cross-wave merge via LDS.
//  - pass 2: recompute scores, write normalized attn (streaming, L2-merged),
//    accumulate PV partials; cross-wave reduce into LDS (aliases Ks).
// ---------------------------------------------------------------------------
__global__ __launch_bounds__(256) void k_attn(
    const float* __restrict__ q_win, const float* __restrict__ kv_win,
    float* __restrict__ attn, float* __restrict__ out_ws)
{
    const int bid = blockIdx.x;
    const int wi = bid >> 3;
    const int h  = bid & 7;
    __shared__ float Ks[16 * 256];
    __shared__ float Vs[16 * 256];
    __shared__ float Mw[4 * 256];
    __shared__ float Lw[4 * 256];
    __shared__ float partial[256];
    __shared__ float rnorm_s[16];
    const int t = threadIdx.x;
    const int wave = t >> 6;
    const int lane = t & 63;

    // ---- load K/V tiles (coalesced float4) ----
    for (int i = t; i < 1024; i += 256) {
        int d = i >> 6, m4 = i & 63;
        int ck = h * 16 + d;
        ((float4*)Ks)[(d << 6) + m4] =
            ((const float4*)kv_win)[((size_t)(ck * 256 + wi) << 6) + m4];
        ((float4*)Vs)[(d << 6) + m4] =
            ((const float4*)kv_win)[((size_t)((ck + 128) * 256 + wi) << 6) + m4];
    }
    __syncthreads();

    // ---- k row norms (over m, per d) ----
    {
        int d = t >> 4, r = t & 15;
        float ssum = 0.f;
        #pragma unroll
        for (int j = 0; j < 16; j++) {
            float v = Ks[d * 256 + r + j * 16];
            ssum += v * v;
        }
        partial[t] = ssum;
    }
    __syncthreads();
    if (t < 16) {
        float ssum = 0.f;
        #pragma unroll
        for (int j = 0; j < 16; j++) ssum += partial[t * 16 + j];
        rnorm_s[t] = 1.f / fmaxf(sqrtf(ssum), 1e-12f);
    }
    __syncthreads();

    // ---- Q -> registers, scaled by rnorm[d] ----
    float qreg[16][4];   // [d][mi]
    const int m0 = lane << 2;
    #pragma unroll
    for (int d = 0; d < 16; d++) {
        float4 qv = *(const float4*)(q_win +
            ((size_t)((h * 16 + d) * 256 + wi) << 8) + m0);
        float rn = rnorm_s[d];
        qreg[d][0] = qv.x * rn; qreg[d][1] = qv.y * rn;
        qreg[d][2] = qv.z * rn; qreg[d][3] = qv.w * rn;
    }

    const int nbase = wave << 6;

    // ---- pass 1: online max / sumexp over this wave's n-range ----
    float M[4] = {-1e30f, -1e30f, -1e30f, -1e30f};
    float L[4] = {0.f, 0.f, 0.f, 0.f};
    for (int nt = 0; nt < 16; nt++) {
        const int n0 = nbase + (nt << 2);
        float s[4][4] = {};
        #pragma unroll
        for (int d = 0; d < 16; d++) {
            float4 kk = *(const float4*)(Ks + d * 256 + n0);  // broadcast
            #pragma unroll
            for (int mi = 0; mi < 4; mi++) {
                float q = qreg[d][mi];
                s[mi][0] += q * kk.x; s[mi][1] += q * kk.y;
                s[mi][2] += q * kk.z; s[mi][3] += q * kk.w;
            }
        }
        #pragma unroll
        for (int mi = 0; mi < 4; mi++) {
            float mx = fmaxf(fmaxf(s[mi][0], s[mi][1]), fmaxf(s[mi][2], s[mi][3]));
            float Mn = fmaxf(M[mi], mx);
            float l = L[mi] * __expf(M[mi] - Mn);
            l += __expf(s[mi][0] - Mn) + __expf(s[mi][1] - Mn)
               + __expf(s[mi][2] - Mn) + __expf(s[mi][3] - Mn);
            L[mi] = l; M[mi] = Mn;
        }
    }
    *(float4*)(Mw + (wave << 8) + m0) = make_float4(M[0], M[1], M[2], M[3]);
    *(float4*)(Lw + (wave << 8) + m0) = make_float4(L[0], L[1], L[2], L[3]);
    __syncthreads();

    // ---- merge M/L across the 4 waves ----
    float Mm[4], Rl[4];
    #pragma unroll
    for (int mi = 0; mi < 4; mi++) {
        const int m = m0 + mi;
        float a0 = Mw[m], a1 = Mw[256 + m], a2 = Mw[512 + m], a3 = Mw[768 + m];
        float Ms = fmaxf(fmaxf(a0, a1), fmaxf(a2, a3));
        float l = Lw[m] * __expf(a0 - Ms) + Lw[256 + m] * __expf(a1 - Ms)
                + Lw[512 + m] * __expf(a2 - Ms) + Lw[768 + m] * __expf(a3 - Ms);
        Mm[mi] = Ms; Rl[mi] = 1.f / l;
    }

    // ---- pass 2: recompute scores, write attn, accumulate PV ----
    float op[16][4] = {};   // [d][mi]
    float* abase = attn + ((size_t)(wi * 8 + h) << 16);
    for (int nt = 0; nt < 16; nt++) {
        const int n0 = nbase + (nt << 2);
        float s[4][4] = {};
        #pragma unroll
        for (int d = 0; d < 16; d++) {
            float4 kk = *(const float4*)(Ks + d * 256 + n0);
            #pragma unroll
            for (int mi = 0; mi < 4; mi++) {
                float q = qreg[d][mi];
                s[mi][0] += q * kk.x; s[mi][1] += q * kk.y;
                s[mi][2] += q * kk.z; s[mi][3] += q * kk.w;
            }
        }
        float p[4][4];
        #pragma unroll
        for (int mi = 0; mi < 4; mi++) {
            p[mi][0] = __expf(s[mi][0] - Mm[mi]) * Rl[mi];
            p[mi][1] = __expf(s[mi][1] - Mm[mi]) * Rl[mi];
            p[mi][2] = __expf(s[mi][2] - Mm[mi]) * Rl[mi];
            p[mi][3] = __expf(s[mi][3] - Mm[mi]) * Rl[mi];
            *(float4*)(abase + ((size_t)(m0 + mi) << 8) + n0) =
                make_float4(p[mi][0], p[mi][1], p[mi][2], p[mi][3]);
        }
        #pragma unroll
        for (int d = 0; d < 16; d++) {
            float4 vv = *(const float4*)(Vs + d * 256 + n0);  // broadcast
            #pragma unroll
            for (int mi = 0; mi < 4; mi++) {
                op[d][mi] += p[mi][0] * vv.x + p[mi][1] * vv.y
                           + p[mi][2] * vv.z + p[mi][3] * vv.w;
            }
        }
    }
    __syncthreads();   // all LDS reads of Ks/Vs done; Ks now aliased as accum

    float* accum = Ks;
    for (int w2 = 0; w2 < 4; w2++) {
        if (wave == w2) {
            #pragma unroll
            for (int d = 0; d < 16; d++) {
                float4* a4 = (float4*)(accum + d * 256 + m0);
                if (w2 == 0) {
                    *a4 = make_float4(op[d][0], op[d][1], op[d][2], op[d][3]);
                } else {
                    float4 v = *a4;
                    v.x += op[d][0]; v.y += op[d][1];
                    v.z += op[d][2]; v.w += op[d][3];
                    *a4 = v;
                }
            }
        }
        __syncthreads();
    }
    // write out (windowed layout, coalesced)
    #pragma unroll
    for (int d = 0; d < 16; d++) {
        out_ws[((size_t)((h * 16 + d) * 256 + wi) << 8) + t] = accum[d * 256 + t];
    }
}

// ---------------------------------------------------------------------------
// Kernel D: un-window out_ws [c][wi][m] -> NCHW image via LDS transpose.
// Block = (c, i2): 16 window-rows staged, 16 image-rows written coalesced.
// ---------------------------------------------------------------------------
__global__ __launch_bounds__(256) void k_unwin(
    const float* __restrict__ src, float* __restrict__ dst)
{
    const int c  = blockIdx.x >> 4;
    const int i2 = blockIdx.x & 15;
    __shared__ float lds[16 * 257];
    const int t = threadIdx.x;
    #pragma unroll
    for (int j2 = 0; j2 < 16; j2++)
        lds[j2 * 257 + t] = src[((size_t)(c * 256 + i2 * 16 + j2) << 8) + t];
    __syncthreads();
    #pragma unroll
    for (int i1 = 0; i1 < 16; i1++) {
        dst[(size_t)c * HW + (i1 * 16 + i2) * 256 + t] =
            lds[(t & 15) * 257 + i1 * 16 + (t >> 4)];
    }
}

// ---------------------------------------------------------------------------
extern "C" void kernel_launch(void* const* d_in, const int* in_sizes, int n_in,
                              void* d_out, int out_size, void* d_ws, size_t ws_size,
                              hipStream_t stream)
{
    const float* lms   = (const float*)d_in[0];
    const float* pan   = (const float*)d_in[1];
    const float* g_ms  = (const float*)d_in[2];
    const float* g_pan = (const float*)d_in[3];
    const float* qw1   = (const float*)d_in[4];
    const float* qb1   = (const float*)d_in[5];
    const float* qw2   = (const float*)d_in[6];
    const float* qb2   = (const float*)d_in[7];
    const float* kvw1  = (const float*)d_in[8];
    const float* kvb1  = (const float*)d_in[9];
    const float* kvw2  = (const float*)d_in[10];
    const float* kvb2  = (const float*)d_in[11];

    float* attn   = (float*)d_out;                       // 256*8*256*256 fp32
    float* outimg = attn + (size_t)134217728;            // 128*256*256 fp32

    char* ws = (char*)d_ws;
    float* q_win  = (float*)(ws);                        //  32 MB [c][wi][m]
    float* kv_win = (float*)(ws + (size_t)33554432);     //  64 MB [c][wi][m]
    float* q_pre  = (float*)(ws + (size_t)100663296);    //  32 MB NCHW
    float* kv_pre = (float*)(ws + (size_t)134217728);    //  64 MB NCHW
    float* out_ws = q_pre;  // overlay: q_pre dead once k_dw3x3(q) is done

    hipLaunchKernelGGL(k_ln_conv1, dim3(256), dim3(256), 0, stream,
                       lms, pan, g_ms, g_pan, qw1, qb1, kvw1, kvb1, q_pre, kv_pre);
    hipLaunchKernelGGL(k_dw3x3, dim3(128 * 32), dim3(256), 0, stream,
                       q_pre, qw2, qb2, q_win);
    hipLaunchKernelGGL(k_dw3x3, dim3(256 * 32), dim3(256), 0, stream,
                       kv_pre, kvw2, kvb2, kv_win);
    hipLaunchKernelGGL(k_attn, dim3(2048), dim3(256), 0, stream,
                       q_win, kv_win, attn, out_ws);
    hipLaunchKernelGGL(k_unwin, dim3(2048), dim3(256), 0, stream,
                       out_ws, outimg);
}